// Round 12
// baseline (440.665 us; speedup 1.0000x reference)
//
#include <hip/hip_runtime.h>

#define L_   2048
#define B_   4
#define D_   1024
#define H_   16
#define DK_  64
#define DFF_ 4096
#define NT_  (L_*B_)   // 8192 tokens

typedef unsigned short u16;
typedef unsigned int   u32;
typedef __bf16 bf16x8 __attribute__((ext_vector_type(8)));
typedef float  f32x4  __attribute__((ext_vector_type(4)));

__device__ __forceinline__ u16 f2bf(float f) {
  u32 u = __float_as_uint(f);
  u += 0x7fffu + ((u >> 16) & 1u);
  return (u16)(u >> 16);
}
__device__ __forceinline__ float bf2f(u32 lo16) {
  return __uint_as_float(lo16 << 16);
}

#define GLDS16(g, l) __builtin_amdgcn_global_load_lds( \
    (const __attribute__((address_space(1))) void*)(g), \
    (__attribute__((address_space(3))) void*)(l), 16, 0, 0)

// log2(e)/sqrt(DK) folded into Q at projection time
#define SCQ_ 0.18033688011112042f

// ---------------- weight transpose f32 [K][N] -> bf16 [N][K] ----------------
__global__ __launch_bounds__(256) void transpose_w_k(
    const float* __restrict__ W, u16* __restrict__ Wt, int K, int N)
{
  __shared__ float tile[32][33];
  int n0 = blockIdx.x * 32, k0 = blockIdx.y * 32;
  int tx = threadIdx.x, ty = threadIdx.y;
#pragma unroll
  for (int i = ty; i < 32; i += 8)
    tile[i][tx] = W[(size_t)(k0 + i) * N + n0 + tx];
  __syncthreads();
#pragma unroll
  for (int i = ty; i < 32; i += 8)
    Wt[(size_t)(n0 + i) * K + k0 + tx] = f2bf(tile[tx][i]);
}

// batched 1024x1024 transpose for Wq,Wk,Wv,Wo -> contiguous dst
__global__ __launch_bounds__(256) void transpose_w4_k(
    const float* __restrict__ W0, const float* __restrict__ W1,
    const float* __restrict__ W2, const float* __restrict__ W3,
    u16* __restrict__ dst)
{
  __shared__ float tile[32][33];
  int z = blockIdx.z;
  const float* W = (z == 0) ? W0 : (z == 1) ? W1 : (z == 2) ? W2 : W3;
  u16* Wt = dst + (size_t)z * 1048576;
  int n0 = blockIdx.x * 32, k0 = blockIdx.y * 32;
  int tx = threadIdx.x, ty = threadIdx.y;
#pragma unroll
  for (int i = ty; i < 32; i += 8)
    tile[i][tx] = W[(size_t)(k0 + i) * 1024 + n0 + tx];
  __syncthreads();
#pragma unroll
  for (int i = ty; i < 32; i += 8)
    Wt[(size_t)(n0 + i) * 1024 + k0 + tx] = f2bf(tile[tx][i]);
}

// ---------------- f32 -> bf16 convert (vectorized) ----------------
__global__ __launch_bounds__(256) void f32_to_bf16_k(
    const float* __restrict__ in, u16* __restrict__ out, int n4)
{
  int i = blockIdx.x * 256 + threadIdx.x;
  if (i >= n4) return;
  float4 v = ((const float4*)in)[i];
  uint2 r;
  r.x = (u32)f2bf(v.x) | ((u32)f2bf(v.y) << 16);
  r.y = (u32)f2bf(v.z) | ((u32)f2bf(v.w) << 16);
  ((uint2*)out)[i] = r;
}

__global__ __launch_bounds__(256) void bias_concat_k(
    const float* __restrict__ bq, const float* __restrict__ bk,
    const float* __restrict__ bv, float* __restrict__ o)
{
  int i = blockIdx.x * 256 + threadIdx.x;
  float v = (i < 1024) ? bq[i] : ((i < 2048) ? bk[i - 1024] : bv[i - 2048]);
  o[i] = v;
}

// ---------------- 256x256 4-phase GEMM (m201-style geometry) ---------------
// C[M][N] = A[M][K] * Bt[N][K]^T. 512 threads = 8 waves (2M x 4N), per-wave
// 128x64 (MIT=8 -> 2.67 MFMA per ds_read_b128), BK=64, 2-deep dbuf (128KB).
// 4 phases per K-tile: {ds_reads ; front-loaded stages ; barrier ;
// lgkmcnt(0)+sched_barrier ; setprio MFMA x16 ; barrier}; stages for t+1 are
// all issued by phase 2, tile-end vmcnt(0) drains loads issued >=1 phase ago.
template<int EPI>
__global__ __launch_bounds__(512, 2)
void gemm8(const u16* __restrict__ A, const u16* __restrict__ Bt,
           const float* __restrict__ bias, const void* __restrict__ res,
           u16* __restrict__ outb, int M, int N, int K)
{
  constexpr int BM = 256, BN = 256, BK = 64;
  constexpr int ABYTES = BM * BK * 2;        // 32768
  constexpr int BUFB = (BM + BN) * BK * 2;   // 65536
  constexpr int NGL = BUFB / 8192;           // 8 glds per K-tile
  __shared__ char SM[2 * BUFB];              // 128KB

  const int tid = threadIdx.x;
  const int w = tid >> 6, lane = tid & 63;
  const int l15 = lane & 15, l4 = lane >> 4;
  const int NK = K >> 6;

  // XCD-bijective block remap (T1)
  const int gx = gridDim.x;
  int nwg = gx * gridDim.y;
  int id = blockIdx.y * gx + blockIdx.x;
  int q = nwg >> 3, r = nwg & 7;
  int xcd = id & 7, idx = id >> 3;
  int wg = (xcd < r ? xcd * (q + 1) : r * (q + 1) + (xcd - r) * q) + idx;
  const int m0 = (wg / gx) * BM, n0 = (wg % gx) * BN;
  const int wm = (w >> 2) * 128, wn = (w & 3) * 64;

  // staging sources: unit u covers LDS bytes [u*8192, +8192); row stride 128B.
  // LDS 16B-slot s of row holds global col8 = s ^ (row&7).
  const u16* gsrc[NGL];
#pragma unroll
  for (int u = 0; u < NGL; ++u) {
    int o = u * 8192 + tid * 16;
    int row; const u16* base;
    if (o < ABYTES) { row = o >> 7; base = A + (size_t)(m0 + row) * K; }
    else { row = (o - ABYTES) >> 7; base = Bt + (size_t)(n0 + row) * K; }
    int col8 = ((o >> 4) & 7) ^ (row & 7);
    gsrc[u] = base + col8 * 8;
  }

  auto stage = [&](int tt, int u, char* dst) {
    GLDS16(gsrc[u] + (size_t)tt * BK, dst + u * 8192 + w * 1024);
  };

  // prologue: tile 0 into buf 0
#pragma unroll
  for (int u = 0; u < NGL; ++u) stage(0, u, SM);
  asm volatile("s_waitcnt vmcnt(0)" ::: "memory");
  __builtin_amdgcn_s_barrier();

  f32x4 acc[8][4];
#pragma unroll
  for (int i = 0; i < 8; ++i)
#pragma unroll
    for (int j = 0; j < 4; ++j) acc[i][j] = (f32x4){0.f, 0.f, 0.f, 0.f};

  for (int t = 0; t < NK; ++t) {
    const char* rb = SM + (t & 1) * BUFB;
    char* wb = SM + ((t + 1) & 1) * BUFB;
    const int tt = (t + 1 < NK) ? t + 1 : 0;   // dummy tail
    bf16x8 bfr[4];
#pragma unroll
    for (int ph = 0; ph < 4; ++ph) {
      const int kk = ph >> 1, mh = ph & 1;
      bf16x8 af[4];
#pragma unroll
      for (int mi = 0; mi < 4; ++mi) {
        int row = wm + mh * 64 + mi * 16 + l15;
        af[mi] = *(const bf16x8*)(rb + row * 128 +
                                  (((kk * 4 + l4) ^ (row & 7)) << 4));
      }
      if (mh == 0) {
#pragma unroll
        for (int nj = 0; nj < 4; ++nj) {
          int row = wn + nj * 16 + l15;
          bfr[nj] = *(const bf16x8*)(rb + ABYTES + row * 128 +
                                     (((kk * 4 + l4) ^ (row & 7)) << 4));
        }
      }
      if (ph == 0)      { stage(tt, 0, wb); stage(tt, 1, wb); stage(tt, 2, wb); }
      else if (ph == 1) { stage(tt, 3, wb); stage(tt, 4, wb); stage(tt, 5, wb); }
      else if (ph == 2) { stage(tt, 6, wb); stage(tt, 7, wb); }
      __builtin_amdgcn_s_barrier();
      asm volatile("s_waitcnt lgkmcnt(0)" ::: "memory");
      __builtin_amdgcn_sched_barrier(0);
      __builtin_amdgcn_s_setprio(1);
#pragma unroll
      for (int mi = 0; mi < 4; ++mi)
#pragma unroll
        for (int nj = 0; nj < 4; ++nj)
          acc[mh * 4 + mi][nj] = __builtin_amdgcn_mfma_f32_16x16x32_bf16(
              af[mi], bfr[nj], acc[mh * 4 + mi][nj], 0, 0, 0);
      __builtin_amdgcn_s_setprio(0);
      if (ph == 3)
        asm volatile("s_waitcnt vmcnt(0)" ::: "memory");  // t+1 landed
      __builtin_amdgcn_s_barrier();
    }
  }
  asm volatile("s_waitcnt vmcnt(0)" ::: "memory");

  // epilogue
  const int gm = m0 + wm + l4 * 4;
  const int gn = n0 + wn + l15;
#pragma unroll
  for (int mi = 0; mi < 8; ++mi) {
#pragma unroll
    for (int nj = 0; nj < 4; ++nj) {
      int col = gn + nj * 16;
      float bv = bias[col];
#pragma unroll
      for (int rr = 0; rr < 4; ++rr) {
        int row = gm + mi * 16 + rr;
        float v = acc[mi][nj][rr] + bv;
        if (EPI == 2) {
          float gv = 0.5f * v * (1.f + erff(v * 0.70710678118654752f));
          outb[(size_t)row * N + col] = f2bf(gv);
        } else if (EPI == 3) {
          int which = col >> 10, c1 = col & 1023;
          int ll = row >> 2, bb = row & 3;
          int hh = c1 >> 6, dd = c1 & 63;
          if (which == 0) v *= SCQ_;
          outb[(size_t)which * 8388608 +
               ((((size_t)(bb * H_ + hh)) * L_ + ll) << 6) + dd] = f2bf(v);
        } else if (EPI == 5) {
          size_t idxo = (size_t)row * N + col;
          outb[idxo] = f2bf(v + ((const float*)res)[idxo]);
        } else {
          size_t idxo = (size_t)row * N + col;
          outb[idxo] = f2bf(v + bf2f(((const u16*)res)[idxo]));
        }
      }
    }
  }
}

// ---------------- r10 256x128 GEMM (kept for Wo/W2, N=1024 grids) ----------
template<int EPI>
__global__ __launch_bounds__(512, 2)
void gemm_pipe(const u16* __restrict__ A, const u16* __restrict__ Bt,
               const float* __restrict__ bias, const void* __restrict__ res,
               u16* __restrict__ outb, int M, int N, int K)
{
  constexpr int BM = 256, BN = 128, BK = 64;
  constexpr int ABYTES = BM * BK * 2;        // 32768
  constexpr int BUFB = (BM + BN) * BK * 2;   // 49152
  __shared__ char SM[3 * BUFB];              // 144KB ring

  const int tid = threadIdx.x;
  const int w = tid >> 6, lane = tid & 63;
  const int l15 = lane & 15, l4 = lane >> 4;
  const int NK = K >> 6;

  const int gx = gridDim.x;
  int nwg = gx * gridDim.y;
  int id = blockIdx.y * gx + blockIdx.x;
  int q = nwg >> 3, r = nwg & 7;
  int xcd = id & 7, idx = id >> 3;
  int wg = (xcd < r ? xcd * (q + 1) : r * (q + 1) + (xcd - r) * q) + idx;
  const int m0 = (wg / gx) * BM, n0 = (wg % gx) * BN;
  const int wm = (w >> 1) * 64, wn = (w & 1) * 64;

  const u16* gsrc[6];
#pragma unroll
  for (int u = 0; u < 6; ++u) {
    int o = u * 8192 + tid * 16;
    int row; const u16* base;
    if (o < ABYTES) {
      row = o >> 7;
      base = A + (size_t)(m0 + row) * K;
    } else {
      int ob = o - ABYTES;
      row = ob >> 7;
      base = Bt + (size_t)(n0 + row) * K;
    }
    int col8 = ((o >> 4) & 7) ^ (row & 7);
    gsrc[u] = base + col8 * 8;
  }

  auto stage = [&](int t, int u) {
    const u16* s = gsrc[u] + (size_t)((t < NK) ? t : 0) * BK;
    GLDS16(s, SM + (t % 3) * BUFB + u * 8192 + w * 1024);
  };

  for (int tt = 0; tt < 2; ++tt)
#pragma unroll
    for (int u = 0; u < 6; ++u) stage(tt, u);
  asm volatile("s_waitcnt vmcnt(6)" ::: "memory");
  asm volatile("s_barrier" ::: "memory");

  f32x4 acc[4][4];
#pragma unroll
  for (int i = 0; i < 4; ++i)
#pragma unroll
    for (int j = 0; j < 4; ++j) acc[i][j] = (f32x4){0.f, 0.f, 0.f, 0.f};

  for (int t = 0; t < NK; ++t) {
    const char* rb = SM + (t % 3) * BUFB;
    const int tn = t + 2;
#pragma unroll
    for (int ph = 0; ph < 2; ++ph) {
      bf16x8 af[4], bfr[4];
#pragma unroll
      for (int mi = 0; mi < 4; ++mi) {
        int row = wm + mi * 16 + l15;
        af[mi] = *(const bf16x8*)(rb + row * 128 +
                                  (((ph * 4 + l4) ^ (l15 & 7)) << 4));
      }
      stage(tn, ph * 3 + 0);
#pragma unroll
      for (int nj = 0; nj < 4; ++nj) {
        int row = wn + nj * 16 + l15;
        bfr[nj] = *(const bf16x8*)(rb + ABYTES + row * 128 +
                                   (((ph * 4 + l4) ^ (l15 & 7)) << 4));
      }
      stage(tn, ph * 3 + 1);
      stage(tn, ph * 3 + 2);
      __builtin_amdgcn_s_setprio(1);
#pragma unroll
      for (int mi = 0; mi < 4; ++mi)
#pragma unroll
        for (int nj = 0; nj < 4; ++nj)
          acc[mi][nj] = __builtin_amdgcn_mfma_f32_16x16x32_bf16(
              af[mi], bfr[nj], acc[mi][nj], 0, 0, 0);
      __builtin_amdgcn_s_setprio(0);
    }
    asm volatile("s_waitcnt lgkmcnt(0)" ::: "memory");
    asm volatile("s_waitcnt vmcnt(6)" ::: "memory");
    asm volatile("s_barrier" ::: "memory");
  }
  asm volatile("s_waitcnt vmcnt(0)" ::: "memory");

  const int gm = m0 + wm + l4 * 4;
  const int gn = n0 + wn + l15;
#pragma unroll
  for (int mi = 0; mi < 4; ++mi) {
#pragma unroll
    for (int nj = 0; nj < 4; ++nj) {
      int col = gn + nj * 16;
      float bv = bias[col];
#pragma unroll
      for (int rr = 0; rr < 4; ++rr) {
        int row = gm + mi * 16 + rr;
        float v = acc[mi][nj][rr] + bv;
        if (EPI == 5) {
          size_t idxo = (size_t)row * N + col;
          outb[idxo] = f2bf(v + ((const float*)res)[idxo]);
        } else {
          size_t idxo = (size_t)row * N + col;
          outb[idxo] = f2bf(v + bf2f(((const u16*)res)[idxo]));
        }
      }
    }
  }
}

// ---------------- flash attention fwd v7: no-max softmax, MFMA row-sums ----
__global__ __launch_bounds__(256, 3)
void attn_fwd2(const u16* __restrict__ qp, const u16* __restrict__ kp,
               const u16* __restrict__ vp, u16* __restrict__ op)
{
  __shared__ u16 Ks[2][64 * 64];
  __shared__ u16 Vt[2][64 * 64];
  const int tid = threadIdx.x, w = tid >> 6, lane = tid & 63;
  const int l15 = lane & 15, l4 = lane >> 4;
  const int n = blockIdx.x;            // 1024 blocks
  const int bh = (n & 7) | ((n >> 7) << 3);
  const int qi = (n >> 3) & 15;
  const int q0 = qi * 128;
  const u16* qb = qp + (size_t)bh * L_ * DK_;
  const u16* kb = kp + (size_t)bh * L_ * DK_;
  const u16* vb = vp + (size_t)bh * L_ * DK_;

  bf16x8 qf[2][2];
#pragma unroll
  for (int g = 0; g < 2; ++g)
#pragma unroll
    for (int kk = 0; kk < 2; ++kk)
      qf[g][kk] = *(const bf16x8*)&qb[(size_t)(q0 + g * 64 + w * 16 + l15) * DK_ +
                                      kk * 32 + l4 * 8];

  f32x4 accO[2][4];
  f32x4 lacc[2];
#pragma unroll
  for (int g = 0; g < 2; ++g) {
#pragma unroll
    for (int i = 0; i < 4; ++i) accO[g][i] = (f32x4){0.f, 0.f, 0.f, 0.f};
    lacc[g] = (f32x4){0.f, 0.f, 0.f, 0.f};
  }

  bf16x8 oneb;
  {
    u32 ob = (l15 == 0) ? 0x3f803f80u : 0u;
#pragma unroll
    for (int j = 0; j < 4; ++j) ((u32*)&oneb)[j] = ob;
  }

  int rho0 = tid >> 3, rho1 = (256 + tid) >> 3, cseg = lane & 7;
  int kv0 = (rho0 & 32) | ((rho0 & 12) << 1) | ((rho0 & 16) >> 2) | (rho0 & 3);
  int kv1 = (rho1 & 32) | ((rho1 & 12) << 1) | ((rho1 & 16) >> 2) | (rho1 & 3);
  const u16* ksrc0 = kb + (size_t)kv0 * DK_ + ((cseg ^ (rho0 & 7)) << 3);
  const u16* ksrc1 = kb + (size_t)kv1 * DK_ + ((cseg ^ (rho1 & 7)) << 3);

  const int vseg = tid & 7, vkvp = tid >> 3;
  const u16* vsrc = vb + (size_t)(vkvp * 2) * DK_ + vseg * 8;
  u32 voff[8];
#pragma unroll
  for (int dd2 = 0; dd2 < 4; ++dd2) {
    int d0 = vseg * 8 + dd2 * 2, d1 = d0 + 1;
    voff[dd2 * 2] = d0 * 128 +
        ((((vkvp >> 2) ^ (d0 & 7) ^ (d0 >> 3)) << 4) | ((vkvp & 3) << 2));
    voff[dd2 * 2 + 1] = d1 * 128 +
        ((((vkvp >> 2) ^ (d1 & 7) ^ (d1 >> 3)) << 4) | ((vkvp & 3) << 2));
  }

  auto packV = [&](int buf, uint4 a, uint4 b) {
#pragma unroll
    for (int dd2 = 0; dd2 < 4; ++dd2) {
      u32 ai = ((const u32*)&a)[dd2], bi = ((const u32*)&b)[dd2];
      *(u32*)((char*)Vt[buf] + voff[dd2 * 2])     = __builtin_amdgcn_perm(bi, ai, 0x05040100u);
      *(u32*)((char*)Vt[buf] + voff[dd2 * 2 + 1]) = __builtin_amdgcn_perm(bi, ai, 0x07060302u);
    }
  };

  auto exp_pack = [&](f32x4 (&s)[4], u32 (&pk)[2][4]) {
#pragma unroll
    for (int i = 0; i < 4; ++i)
#pragma unroll
      for (int rr = 0; rr < 4; ++rr) s[i][rr] = exp2f(s[i][rr]);
#pragma unroll
    for (int kk = 0; kk < 2; ++kk)
#pragma unroll
      for (int j2 = 0; j2 < 4; ++j2) {
        int nb = kk * 2 + (j2 >> 1);
        int rr = (j2 & 1) * 2;
        u32 rres;
        asm("v_cvt_pk_bf16_f32 %0, %1, %2" : "=v"(rres)
            : "v"(s[nb][rr]), "v"(s[nb][rr + 1]));
        pk[kk][j2] = rres;
      }
  };

  {
    uint4 a = *(const uint4*)vsrc;
    uint4 b = *(const uint4*)(vsrc + DK_);
    GLDS16(ksrc0, &Ks[0][w * 512]);
    GLDS16(ksrc1, &Ks[0][2048 + w * 512]);
    packV(0, a, b);
  }
  __syncthreads();

  constexpr int NTI = L_ / 64;   // 32
  for (int t = 0; t < NTI; ++t) {
    const int cur = t & 1;
    const bool pf = (t + 1 < NTI);
    const int tn = pf ? t + 1 : t;

    uint4 va = *(const uint4*)(vsrc + (size_t)(tn * 64) * DK_);
    uint4 vbv = *(const uint4*)(vsrc + (size_t)(tn * 64) * DK_ + DK_);
    if (pf) {
      GLDS16(ksrc0 + (size_t)((t + 1) * 64) * DK_, &Ks[cur ^ 1][w * 512]);
      GLDS16(ksrc1 + (size_t)((t + 1) * 64) * DK_, &Ks[cur ^ 1][2048 + w * 512]);
    }

    f32x4 s0[4], s1[4];
#pragma unroll
    for (int i = 0; i < 4; ++i) {
      s0[i] = (f32x4){0.f, 0.f, 0.f, 0.f};
      s1[i] = (f32x4){0.f, 0.f, 0.f, 0.f};
    }
#pragma unroll
    for (int kk = 0; kk < 2; ++kk) {
#pragma unroll
      for (int nb = 0; nb < 4; ++nb) {
        int row = nb * 16 + l15;
        bf16x8 kf = *(const bf16x8*)((const char*)Ks[cur] + row * 128 +
                                     (((kk * 4 + l4) ^ (row & 7)) << 4));
        s0[nb] = __builtin_amdgcn_mfma_f32_16x16x32_bf16(kf, qf[0][kk], s0[nb], 0, 0, 0);
        s1[nb] = __builtin_amdgcn_mfma_f32_16x16x32_bf16(kf, qf[1][kk], s1[nb], 0, 0, 0);
      }
    }

    u32 pk0[2][4], pk1[2][4];
    exp_pack(s0, pk0);
    exp_pack(s1, pk1);

    if (pf) packV(cur ^ 1, va, vbv);

#pragma unroll
    for (int kk = 0; kk < 2; ++kk) {
      bf16x8 pa0, pa1;
      ((u32*)&pa0)[0] = pk0[kk][0]; ((u32*)&pa0)[1] = pk0[kk][1];
      ((u32*)&pa0)[2] = pk0[kk][2]; ((u32*)&pa0)[3] = pk0[kk][3];
      ((u32*)&pa1)[0] = pk1[kk][0]; ((u32*)&pa1)[1] = pk1[kk][1];
      ((u32*)&pa1)[2] = pk1[kk][2]; ((u32*)&pa1)[3] = pk1[kk][3];
      lacc[0] = __builtin_amdgcn_mfma_f32_16x16x32_bf16(pa0, oneb, lacc[0], 0, 0, 0);
      lacc[1] = __builtin_amdgcn_mfma_f32_16x16x32_bf16(pa1, oneb, lacc[1], 0, 0, 0);
#pragma unroll
      for (int nb2 = 0; nb2 < 4; ++nb2) {
        int drow = nb2 * 16 + l15;
        bf16x8 vf = *(const bf16x8*)((const char*)Vt[cur] + drow * 128 +
                                     (((kk * 4 + l4) ^ (drow & 7) ^ (drow >> 3)) << 4));
        accO[0][nb2] = __builtin_amdgcn_mfma_f32_16x16x32_bf16(pa0, vf, accO[0][nb2], 0, 0, 0);
        accO[1][nb2] = __builtin_amdgcn_mfma_f32_16x16x32_bf16(pa1, vf, accO[1][nb2], 0, 0, 0);
      }
    }
    __syncthreads();
  }

  const int bb = bh >> 4, hh = bh & 15;
#pragma unroll
  for (int g = 0; g < 2; ++g) {
#pragma unroll
    for (int rr = 0; rr < 4; ++rr) {
      float ls = __shfl(lacc[g][rr], l4 << 4);
      float rl = 1.f / ls;
      int qg = q0 + g * 64 + w * 16 + l4 * 4 + rr;
      size_t base = ((size_t)qg * B_ + bb) * D_ + hh * 64;
#pragma unroll
      for (int nb2 = 0; nb2 < 4; ++nb2)
        op[base + nb2 * 16 + l15] = f2bf(accO[g][nb2][rr] * rl);
    }
  }
}

// ---------------- layernorm over last dim (D=1024), bf16 input ----------------
__global__ __launch_bounds__(256) void layernorm_bf_k(
    const u16* __restrict__ y, const float* __restrict__ g, const float* __restrict__ be,
    float* __restrict__ of, u16* __restrict__ ob)
{
  int row = blockIdx.x, tid = threadIdx.x;
  uint2 raw = *(const uint2*)&y[(size_t)row * D_ + tid * 4];
  float v0 = bf2f(raw.x & 0xffffu), v1 = bf2f(raw.x >> 16);
  float v2 = bf2f(raw.y & 0xffffu), v3 = bf2f(raw.y >> 16);
  float s = (v0 + v1) + (v2 + v3);
  float ss = v0 * v0 + v1 * v1 + v2 * v2 + v3 * v3;
#pragma unroll
  for (int msk = 32; msk >= 1; msk >>= 1) {
    s += __shfl_xor(s, msk);
    ss += __shfl_xor(ss, msk);
  }
  __shared__ float rs[4], rss[4];
  if ((tid & 63) == 0) { rs[tid >> 6] = s; rss[tid >> 6] = ss; }
  __syncthreads();
  s = rs[0] + rs[1] + rs[2] + rs[3];
  ss = rss[0] + rss[1] + rss[2] + rss[3];
  float mu = s * (1.f / D_);
  float var = ss * (1.f / D_) - mu * mu;
  float rstd = rsqrtf(var + 1e-5f);
  int c = tid * 4;
  float o0 = (v0 - mu) * rstd * g[c + 0] + be[c + 0];
  float o1 = (v1 - mu) * rstd * g[c + 1] + be[c + 1];
  float o2 = (v2 - mu) * rstd * g[c + 2] + be[c + 2];
  float o3 = (v3 - mu) * rstd * g[c + 3] + be[c + 3];
  if (of) {
    float4 o = {o0, o1, o2, o3};
    *(float4*)&of[(size_t)row * D_ + c] = o;
  }
  if (ob) {
    uint2 r;
    r.x = (u32)f2bf(o0) | ((u32)f2bf(o1) << 16);
    r.y = (u32)f2bf(o2) | ((u32)f2bf(o3) << 16);
    *(uint2*)&ob[(size_t)row * D_ + c] = r;
  }
}

// ---------------- launch ----------------
extern "C" void kernel_launch(void* const* d_in, const int* in_sizes, int n_in,
                              void* d_out, int out_size, void* d_ws, size_t ws_size,
                              hipStream_t stream)
{
  const float* x   = (const float*)d_in[0];
  const float* Wq  = (const float*)d_in[1];
  const float* bq  = (const float*)d_in[2];
  const float* Wk  = (const float*)d_in[3];
  const float* bk  = (const float*)d_in[4];
  const float* Wv  = (const float*)d_in[5];
  const float* bv  = (const float*)d_in[6];
  const float* Wo  = (const float*)d_in[7];
  const float* bo  = (const float*)d_in[8];
  const float* W1f = (const float*)d_in[9];
  const float* b1  = (const float*)d_in[10];
  const float* W2f = (const float*)d_in[11];
  const float* b2  = (const float*)d_in[12];
  const float* g1  = (const float*)d_in[13];
  const float* be1 = (const float*)d_in[14];
  const float* g2  = (const float*)d_in[15];
  const float* be2 = (const float*)d_in[16];

  char* ws = (char*)d_ws;
  const size_t MB = 1024 * 1024;
  u16* WqT  = (u16*)(ws + 0 * MB);      // 8MB: WqT,WkT,WvT,WoT contiguous
  u16* WoT  = (u16*)(ws + 6 * MB);
  u16* W1T  = (u16*)(ws + 8 * MB);      // 8MB
  u16* W2T  = (u16*)(ws + 16 * MB);     // 8MB
  u16* xb   = (u16*)(ws + 24 * MB);     // 16MB
  u16* qp   = (u16*)(ws + 40 * MB);     // 48MB: qp,kp,vp
  u16* astd = (u16*)(ws + 88 * MB);     // 16MB
  u16* yb   = (u16*)(ws + 104 * MB);    // 16MB
  u16* x1b  = (u16*)(ws + 120 * MB);    // 16MB
  u16* hbuf = (u16*)(ws + 136 * MB);    // 64MB
  float* bcat = (float*)(ws + 200 * MB);// 12KB
  u16* kp = qp + 8388608;
  u16* vp = qp + 16777216;

  dim3 tb(32, 8);
  transpose_w4_k<<<dim3(32, 32, 4), tb, 0, stream>>>(Wq, Wk, Wv, Wo, WqT);
  transpose_w_k<<<dim3(128, 32), tb, 0, stream>>>(W1f, W1T, D_, DFF_);
  transpose_w_k<<<dim3(32, 128), tb, 0, stream>>>(W2f, W2T, DFF_, D_);
  f32_to_bf16_k<<<NT_ * D_ / 4 / 256, 256, 0, stream>>>(x, xb, NT_ * D_ / 4);
  bias_concat_k<<<12, 256, 0, stream>>>(bq, bk, bv, bcat);

  // fused QKV: [8192 x 3072], scattered to [b][h][l][d]; Q pre-scaled (256² tile)
  gemm8<3><<<dim3(12, 32), 512, 0, stream>>>(
      xb, WqT, bcat, nullptr, qp, NT_, 3072, D_);

  attn_fwd2<<<1024, 256, 0, stream>>>(qp, kp, vp, astd);

  gemm_pipe<5><<<dim3(8, 32), 512, 0, stream>>>(
      astd, WoT, bo, x, yb, NT_, D_, D_);
  layernorm_bf_k<<<NT_, 256, 0, stream>>>(yb, g1, be1, nullptr, x1b);
  gemm8<2><<<dim3(16, 32), 512, 0, stream>>>(
      x1b, W1T, b1, nullptr, hbuf, NT_, DFF_, D_);
  gemm_pipe<6><<<dim3(8, 32), 512, 0, stream>>>(
      hbuf, W2T, b2, x1b, yb, NT_, D_, DFF_);
  layernorm_bf_k<<<NT_, 256, 0, stream>>>(yb, g2, be2, (float*)d_out, nullptr);
}

// Round 13
// 439.475 us; speedup vs baseline: 1.0027x; 1.0027x over previous
//
#include <hip/hip_runtime.h>

#define L_   2048
#define B_   4
#define D_   1024
#define H_   16
#define DK_  64
#define DFF_ 4096
#define NT_  (L_*B_)   // 8192 tokens

typedef unsigned short u16;
typedef unsigned int   u32;
typedef __bf16 bf16x8 __attribute__((ext_vector_type(8)));
typedef float  f32x4  __attribute__((ext_vector_type(4)));

__device__ __forceinline__ u16 f2bf(float f) {
  u32 u = __float_as_uint(f);
  u += 0x7fffu + ((u >> 16) & 1u);
  return (u16)(u >> 16);
}
__device__ __forceinline__ float bf2f(u32 lo16) {
  return __uint_as_float(lo16 << 16);
}

#define GLDS16(g, l) __builtin_amdgcn_global_load_lds( \
    (const __attribute__((address_space(1))) void*)(g), \
    (__attribute__((address_space(3))) void*)(l), 16, 0, 0)

// log2(e)/sqrt(DK) folded into Q at projection time
#define SCQ_ 0.18033688011112042f

// ---------------- weight transpose f32 [K][N] -> bf16 [N][K] ----------------
__global__ __launch_bounds__(256) void transpose_w_k(
    const float* __restrict__ W, u16* __restrict__ Wt, int K, int N)
{
  __shared__ float tile[32][33];
  int n0 = blockIdx.x * 32, k0 = blockIdx.y * 32;
  int tx = threadIdx.x, ty = threadIdx.y;
#pragma unroll
  for (int i = ty; i < 32; i += 8)
    tile[i][tx] = W[(size_t)(k0 + i) * N + n0 + tx];
  __syncthreads();
#pragma unroll
  for (int i = ty; i < 32; i += 8)
    Wt[(size_t)(n0 + i) * K + k0 + tx] = f2bf(tile[tx][i]);
}

// batched 1024x1024 transpose for Wq,Wk,Wv,Wo -> contiguous dst
__global__ __launch_bounds__(256) void transpose_w4_k(
    const float* __restrict__ W0, const float* __restrict__ W1,
    const float* __restrict__ W2, const float* __restrict__ W3,
    u16* __restrict__ dst)
{
  __shared__ float tile[32][33];
  int z = blockIdx.z;
  const float* W = (z == 0) ? W0 : (z == 1) ? W1 : (z == 2) ? W2 : W3;
  u16* Wt = dst + (size_t)z * 1048576;
  int n0 = blockIdx.x * 32, k0 = blockIdx.y * 32;
  int tx = threadIdx.x, ty = threadIdx.y;
#pragma unroll
  for (int i = ty; i < 32; i += 8)
    tile[i][tx] = W[(size_t)(k0 + i) * 1024 + n0 + tx];
  __syncthreads();
#pragma unroll
  for (int i = ty; i < 32; i += 8)
    Wt[(size_t)(n0 + i) * 1024 + k0 + tx] = f2bf(tile[tx][i]);
}

// ---------------- f32 -> bf16 convert (vectorized) ----------------
__global__ __launch_bounds__(256) void f32_to_bf16_k(
    const float* __restrict__ in, u16* __restrict__ out, int n4)
{
  int i = blockIdx.x * 256 + threadIdx.x;
  if (i >= n4) return;
  float4 v = ((const float4*)in)[i];
  uint2 r;
  r.x = (u32)f2bf(v.x) | ((u32)f2bf(v.y) << 16);
  r.y = (u32)f2bf(v.z) | ((u32)f2bf(v.w) << 16);
  ((uint2*)out)[i] = r;
}

__global__ __launch_bounds__(256) void bias_concat_k(
    const float* __restrict__ bq, const float* __restrict__ bk,
    const float* __restrict__ bv, float* __restrict__ o)
{
  int i = blockIdx.x * 256 + threadIdx.x;
  float v = (i < 1024) ? bq[i] : ((i < 2048) ? bk[i - 1024] : bv[i - 2048]);
  o[i] = v;
}

// ---------------- 256x256 4-phase GEMM (m201-style geometry) ---------------
// C[M][N] = A[M][K] * Bt[N][K]^T. 512 threads = 8 waves (2M x 4N), per-wave
// 128x64 (MIT=8 -> 2.67 MFMA per ds_read_b128), BK=64, 2-deep dbuf (128KB).
// 4 phases per K-tile: {ds_reads ; front-loaded stages ; barrier ;
// lgkmcnt(0)+sched_barrier ; setprio MFMA x16 ; barrier}; stages for t+1 are
// all issued by phase 2, tile-end vmcnt(0) drains loads issued >=1 phase ago.
template<int EPI>
__global__ __launch_bounds__(512, 2)
void gemm8(const u16* __restrict__ A, const u16* __restrict__ Bt,
           const float* __restrict__ bias, const void* __restrict__ res,
           u16* __restrict__ outb, int M, int N, int K)
{
  constexpr int BM = 256, BN = 256, BK = 64;
  constexpr int ABYTES = BM * BK * 2;        // 32768
  constexpr int BUFB = (BM + BN) * BK * 2;   // 65536
  constexpr int NGL = BUFB / 8192;           // 8 glds per K-tile
  __shared__ char SM[2 * BUFB];              // 128KB

  const int tid = threadIdx.x;
  const int w = tid >> 6, lane = tid & 63;
  const int l15 = lane & 15, l4 = lane >> 4;
  const int NK = K >> 6;

  // XCD-bijective block remap (T1)
  const int gx = gridDim.x;
  int nwg = gx * gridDim.y;
  int id = blockIdx.y * gx + blockIdx.x;
  int q = nwg >> 3, r = nwg & 7;
  int xcd = id & 7, idx = id >> 3;
  int wg = (xcd < r ? xcd * (q + 1) : r * (q + 1) + (xcd - r) * q) + idx;
  const int m0 = (wg / gx) * BM, n0 = (wg % gx) * BN;
  const int wm = (w >> 2) * 128, wn = (w & 3) * 64;

  // staging sources: unit u covers LDS bytes [u*8192, +8192); row stride 128B.
  // LDS 16B-slot s of row holds global col8 = s ^ (row&7).
  const u16* gsrc[NGL];
#pragma unroll
  for (int u = 0; u < NGL; ++u) {
    int o = u * 8192 + tid * 16;
    int row; const u16* base;
    if (o < ABYTES) { row = o >> 7; base = A + (size_t)(m0 + row) * K; }
    else { row = (o - ABYTES) >> 7; base = Bt + (size_t)(n0 + row) * K; }
    int col8 = ((o >> 4) & 7) ^ (row & 7);
    gsrc[u] = base + col8 * 8;
  }

  auto stage = [&](int tt, int u, char* dst) {
    GLDS16(gsrc[u] + (size_t)tt * BK, dst + u * 8192 + w * 1024);
  };

  // prologue: tile 0 into buf 0
#pragma unroll
  for (int u = 0; u < NGL; ++u) stage(0, u, SM);
  asm volatile("s_waitcnt vmcnt(0)" ::: "memory");
  __builtin_amdgcn_s_barrier();

  f32x4 acc[8][4];
#pragma unroll
  for (int i = 0; i < 8; ++i)
#pragma unroll
    for (int j = 0; j < 4; ++j) acc[i][j] = (f32x4){0.f, 0.f, 0.f, 0.f};

  for (int t = 0; t < NK; ++t) {
    const char* rb = SM + (t & 1) * BUFB;
    char* wb = SM + ((t + 1) & 1) * BUFB;
    const int tt = (t + 1 < NK) ? t + 1 : 0;   // dummy tail
    bf16x8 bfr[4];
#pragma unroll
    for (int ph = 0; ph < 4; ++ph) {
      const int kk = ph >> 1, mh = ph & 1;
      bf16x8 af[4];
#pragma unroll
      for (int mi = 0; mi < 4; ++mi) {
        int row = wm + mh * 64 + mi * 16 + l15;
        af[mi] = *(const bf16x8*)(rb + row * 128 +
                                  (((kk * 4 + l4) ^ (row & 7)) << 4));
      }
      if (mh == 0) {
#pragma unroll
        for (int nj = 0; nj < 4; ++nj) {
          int row = wn + nj * 16 + l15;
          bfr[nj] = *(const bf16x8*)(rb + ABYTES + row * 128 +
                                     (((kk * 4 + l4) ^ (row & 7)) << 4));
        }
      }
      if (ph == 0)      { stage(tt, 0, wb); stage(tt, 1, wb); stage(tt, 2, wb); }
      else if (ph == 1) { stage(tt, 3, wb); stage(tt, 4, wb); stage(tt, 5, wb); }
      else if (ph == 2) { stage(tt, 6, wb); stage(tt, 7, wb); }
      __builtin_amdgcn_s_barrier();
      asm volatile("s_waitcnt lgkmcnt(0)" ::: "memory");
      __builtin_amdgcn_sched_barrier(0);
      __builtin_amdgcn_s_setprio(1);
#pragma unroll
      for (int mi = 0; mi < 4; ++mi)
#pragma unroll
        for (int nj = 0; nj < 4; ++nj)
          acc[mh * 4 + mi][nj] = __builtin_amdgcn_mfma_f32_16x16x32_bf16(
              af[mi], bfr[nj], acc[mh * 4 + mi][nj], 0, 0, 0);
      __builtin_amdgcn_s_setprio(0);
      if (ph == 3)
        asm volatile("s_waitcnt vmcnt(0)" ::: "memory");  // t+1 landed
      __builtin_amdgcn_s_barrier();
    }
  }
  asm volatile("s_waitcnt vmcnt(0)" ::: "memory");

  // epilogue
  const int gm = m0 + wm + l4 * 4;
  const int gn = n0 + wn + l15;
#pragma unroll
  for (int mi = 0; mi < 8; ++mi) {
#pragma unroll
    for (int nj = 0; nj < 4; ++nj) {
      int col = gn + nj * 16;
      float bv = bias[col];
#pragma unroll
      for (int rr = 0; rr < 4; ++rr) {
        int row = gm + mi * 16 + rr;
        float v = acc[mi][nj][rr] + bv;
        if (EPI == 2) {
          float gv = 0.5f * v * (1.f + erff(v * 0.70710678118654752f));
          outb[(size_t)row * N + col] = f2bf(gv);
        } else if (EPI == 3) {
          int which = col >> 10, c1 = col & 1023;
          int ll = row >> 2, bb = row & 3;
          int hh = c1 >> 6, dd = c1 & 63;
          if (which == 0) v *= SCQ_;
          outb[(size_t)which * 8388608 +
               ((((size_t)(bb * H_ + hh)) * L_ + ll) << 6) + dd] = f2bf(v);
        } else if (EPI == 5) {
          size_t idxo = (size_t)row * N + col;
          outb[idxo] = f2bf(v + ((const float*)res)[idxo]);
        } else {
          size_t idxo = (size_t)row * N + col;
          outb[idxo] = f2bf(v + bf2f(((const u16*)res)[idxo]));
        }
      }
    }
  }
}

// ---------------- r10 256x128 GEMM (kept for Wo/W2, N=1024 grids) ----------
template<int EPI>
__global__ __launch_bounds__(512, 2)
void gemm_pipe(const u16* __restrict__ A, const u16* __restrict__ Bt,
               const float* __restrict__ bias, const void* __restrict__ res,
               u16* __restrict__ outb, int M, int N, int K)
{
  constexpr int BM = 256, BN = 128, BK = 64;
  constexpr int ABYTES = BM * BK * 2;        // 32768
  constexpr int BUFB = (BM + BN) * BK * 2;   // 49152
  __shared__ char SM[3 * BUFB];              // 144KB ring

  const int tid = threadIdx.x;
  const int w = tid >> 6, lane = tid & 63;
  const int l15 = lane & 15, l4 = lane >> 4;
  const int NK = K >> 6;

  const int gx = gridDim.x;
  int nwg = gx * gridDim.y;
  int id = blockIdx.y * gx + blockIdx.x;
  int q = nwg >> 3, r = nwg & 7;
  int xcd = id & 7, idx = id >> 3;
  int wg = (xcd < r ? xcd * (q + 1) : r * (q + 1) + (xcd - r) * q) + idx;
  const int m0 = (wg / gx) * BM, n0 = (wg % gx) * BN;
  const int wm = (w >> 1) * 64, wn = (w & 1) * 64;

  const u16* gsrc[6];
#pragma unroll
  for (int u = 0; u < 6; ++u) {
    int o = u * 8192 + tid * 16;
    int row; const u16* base;
    if (o < ABYTES) {
      row = o >> 7;
      base = A + (size_t)(m0 + row) * K;
    } else {
      int ob = o - ABYTES;
      row = ob >> 7;
      base = Bt + (size_t)(n0 + row) * K;
    }
    int col8 = ((o >> 4) & 7) ^ (row & 7);
    gsrc[u] = base + col8 * 8;
  }

  auto stage = [&](int t, int u) {
    const u16* s = gsrc[u] + (size_t)((t < NK) ? t : 0) * BK;
    GLDS16(s, SM + (t % 3) * BUFB + u * 8192 + w * 1024);
  };

  for (int tt = 0; tt < 2; ++tt)
#pragma unroll
    for (int u = 0; u < 6; ++u) stage(tt, u);
  asm volatile("s_waitcnt vmcnt(6)" ::: "memory");
  asm volatile("s_barrier" ::: "memory");

  f32x4 acc[4][4];
#pragma unroll
  for (int i = 0; i < 4; ++i)
#pragma unroll
    for (int j = 0; j < 4; ++j) acc[i][j] = (f32x4){0.f, 0.f, 0.f, 0.f};

  for (int t = 0; t < NK; ++t) {
    const char* rb = SM + (t % 3) * BUFB;
    const int tn = t + 2;
#pragma unroll
    for (int ph = 0; ph < 2; ++ph) {
      bf16x8 af[4], bfr[4];
#pragma unroll
      for (int mi = 0; mi < 4; ++mi) {
        int row = wm + mi * 16 + l15;
        af[mi] = *(const bf16x8*)(rb + row * 128 +
                                  (((ph * 4 + l4) ^ (l15 & 7)) << 4));
      }
      stage(tn, ph * 3 + 0);
#pragma unroll
      for (int nj = 0; nj < 4; ++nj) {
        int row = wn + nj * 16 + l15;
        bfr[nj] = *(const bf16x8*)(rb + ABYTES + row * 128 +
                                   (((ph * 4 + l4) ^ (l15 & 7)) << 4));
      }
      stage(tn, ph * 3 + 1);
      stage(tn, ph * 3 + 2);
      __builtin_amdgcn_s_setprio(1);
#pragma unroll
      for (int mi = 0; mi < 4; ++mi)
#pragma unroll
        for (int nj = 0; nj < 4; ++nj)
          acc[mi][nj] = __builtin_amdgcn_mfma_f32_16x16x32_bf16(
              af[mi], bfr[nj], acc[mi][nj], 0, 0, 0);
      __builtin_amdgcn_s_setprio(0);
    }
    asm volatile("s_waitcnt lgkmcnt(0)" ::: "memory");
    asm volatile("s_waitcnt vmcnt(6)" ::: "memory");
    asm volatile("s_barrier" ::: "memory");
  }
  asm volatile("s_waitcnt vmcnt(0)" ::: "memory");

  const int gm = m0 + wm + l4 * 4;
  const int gn = n0 + wn + l15;
#pragma unroll
  for (int mi = 0; mi < 4; ++mi) {
#pragma unroll
    for (int nj = 0; nj < 4; ++nj) {
      int col = gn + nj * 16;
      float bv = bias[col];
#pragma unroll
      for (int rr = 0; rr < 4; ++rr) {
        int row = gm + mi * 16 + rr;
        float v = acc[mi][nj][rr] + bv;
        if (EPI == 5) {
          size_t idxo = (size_t)row * N + col;
          outb[idxo] = f2bf(v + ((const float*)res)[idxo]);
        } else {
          size_t idxo = (size_t)row * N + col;
          outb[idxo] = f2bf(v + bf2f(((const u16*)res)[idxo]));
        }
      }
    }
  }
}

// ---------------- flash attention fwd v7: no-max softmax, MFMA row-sums ----
__global__ __launch_bounds__(256, 3)
void attn_fwd2(const u16* __restrict__ qp, const u16* __restrict__ kp,
               const u16* __restrict__ vp, u16* __restrict__ op)
{
  __shared__ u16 Ks[2][64 * 64];
  __shared__ u16 Vt[2][64 * 64];
  const int tid = threadIdx.x, w = tid >> 6, lane = tid & 63;
  const int l15 = lane & 15, l4 = lane >> 4;
  const int n = blockIdx.x;            // 1024 blocks
  const int bh = (n & 7) | ((n >> 7) << 3);
  const int qi = (n >> 3) & 15;
  const int q0 = qi * 128;
  const u16* qb = qp + (size_t)bh * L_ * DK_;
  const u16* kb = kp + (size_t)bh * L_ * DK_;
  const u16* vb = vp + (size_t)bh * L_ * DK_;

  bf16x8 qf[2][2];
#pragma unroll
  for (int g = 0; g < 2; ++g)
#pragma unroll
    for (int kk = 0; kk < 2; ++kk)
      qf[g][kk] = *(const bf16x8*)&qb[(size_t)(q0 + g * 64 + w * 16 + l15) * DK_ +
                                      kk * 32 + l4 * 8];

  f32x4 accO[2][4];
  f32x4 lacc[2];
#pragma unroll
  for (int g = 0; g < 2; ++g) {
#pragma unroll
    for (int i = 0; i < 4; ++i) accO[g][i] = (f32x4){0.f, 0.f, 0.f, 0.f};
    lacc[g] = (f32x4){0.f, 0.f, 0.f, 0.f};
  }

  bf16x8 oneb;
  {
    u32 ob = (l15 == 0) ? 0x3f803f80u : 0u;
#pragma unroll
    for (int j = 0; j < 4; ++j) ((u32*)&oneb)[j] = ob;
  }

  int rho0 = tid >> 3, rho1 = (256 + tid) >> 3, cseg = lane & 7;
  int kv0 = (rho0 & 32) | ((rho0 & 12) << 1) | ((rho0 & 16) >> 2) | (rho0 & 3);
  int kv1 = (rho1 & 32) | ((rho1 & 12) << 1) | ((rho1 & 16) >> 2) | (rho1 & 3);
  const u16* ksrc0 = kb + (size_t)kv0 * DK_ + ((cseg ^ (rho0 & 7)) << 3);
  const u16* ksrc1 = kb + (size_t)kv1 * DK_ + ((cseg ^ (rho1 & 7)) << 3);

  const int vseg = tid & 7, vkvp = tid >> 3;
  const u16* vsrc = vb + (size_t)(vkvp * 2) * DK_ + vseg * 8;
  u32 voff[8];
#pragma unroll
  for (int dd2 = 0; dd2 < 4; ++dd2) {
    int d0 = vseg * 8 + dd2 * 2, d1 = d0 + 1;
    voff[dd2 * 2] = d0 * 128 +
        ((((vkvp >> 2) ^ (d0 & 7) ^ (d0 >> 3)) << 4) | ((vkvp & 3) << 2));
    voff[dd2 * 2 + 1] = d1 * 128 +
        ((((vkvp >> 2) ^ (d1 & 7) ^ (d1 >> 3)) << 4) | ((vkvp & 3) << 2));
  }

  auto packV = [&](int buf, uint4 a, uint4 b) {
#pragma unroll
    for (int dd2 = 0; dd2 < 4; ++dd2) {
      u32 ai = ((const u32*)&a)[dd2], bi = ((const u32*)&b)[dd2];
      *(u32*)((char*)Vt[buf] + voff[dd2 * 2])     = __builtin_amdgcn_perm(bi, ai, 0x05040100u);
      *(u32*)((char*)Vt[buf] + voff[dd2 * 2 + 1]) = __builtin_amdgcn_perm(bi, ai, 0x07060302u);
    }
  };

  auto exp_pack = [&](f32x4 (&s)[4], u32 (&pk)[2][4]) {
#pragma unroll
    for (int i = 0; i < 4; ++i)
#pragma unroll
      for (int rr = 0; rr < 4; ++rr) s[i][rr] = exp2f(s[i][rr]);
#pragma unroll
    for (int kk = 0; kk < 2; ++kk)
#pragma unroll
      for (int j2 = 0; j2 < 4; ++j2) {
        int nb = kk * 2 + (j2 >> 1);
        int rr = (j2 & 1) * 2;
        u32 rres;
        asm("v_cvt_pk_bf16_f32 %0, %1, %2" : "=v"(rres)
            : "v"(s[nb][rr]), "v"(s[nb][rr + 1]));
        pk[kk][j2] = rres;
      }
  };

  {
    uint4 a = *(const uint4*)vsrc;
    uint4 b = *(const uint4*)(vsrc + DK_);
    GLDS16(ksrc0, &Ks[0][w * 512]);
    GLDS16(ksrc1, &Ks[0][2048 + w * 512]);
    packV(0, a, b);
  }
  __syncthreads();

  constexpr int NTI = L_ / 64;   // 32
  for (int t = 0; t < NTI; ++t) {
    const int cur = t & 1;
    const bool pf = (t + 1 < NTI);
    const int tn = pf ? t + 1 : t;

    uint4 va = *(const uint4*)(vsrc + (size_t)(tn * 64) * DK_);
    uint4 vbv = *(const uint4*)(vsrc + (size_t)(tn * 64) * DK_ + DK_);
    if (pf) {
      GLDS16(ksrc0 + (size_t)((t + 1) * 64) * DK_, &Ks[cur ^ 1][w * 512]);
      GLDS16(ksrc1 + (size_t)((t + 1) * 64) * DK_, &Ks[cur ^ 1][2048 + w * 512]);
    }

    f32x4 s0[4], s1[4];
#pragma unroll
    for (int i = 0; i < 4; ++i) {
      s0[i] = (f32x4){0.f, 0.f, 0.f, 0.f};
      s1[i] = (f32x4){0.f, 0.f, 0.f, 0.f};
    }
#pragma unroll
    for (int kk = 0; kk < 2; ++kk) {
#pragma unroll
      for (int nb = 0; nb < 4; ++nb) {
        int row = nb * 16 + l15;
        bf16x8 kf = *(const bf16x8*)((const char*)Ks[cur] + row * 128 +
                                     (((kk * 4 + l4) ^ (row & 7)) << 4));
        s0[nb] = __builtin_amdgcn_mfma_f32_16x16x32_bf16(kf, qf[0][kk], s0[nb], 0, 0, 0);
        s1[nb] = __builtin_amdgcn_mfma_f32_16x16x32_bf16(kf, qf[1][kk], s1[nb], 0, 0, 0);
      }
    }

    u32 pk0[2][4], pk1[2][4];
    exp_pack(s0, pk0);
    exp_pack(s1, pk1);

    if (pf) packV(cur ^ 1, va, vbv);

#pragma unroll
    for (int kk = 0; kk < 2; ++kk) {
      bf16x8 pa0, pa1;
      ((u32*)&pa0)[0] = pk0[kk][0]; ((u32*)&pa0)[1] = pk0[kk][1];
      ((u32*)&pa0)[2] = pk0[kk][2]; ((u32*)&pa0)[3] = pk0[kk][3];
      ((u32*)&pa1)[0] = pk1[kk][0]; ((u32*)&pa1)[1] = pk1[kk][1];
      ((u32*)&pa1)[2] = pk1[kk][2]; ((u32*)&pa1)[3] = pk1[kk][3];
      lacc[0] = __builtin_amdgcn_mfma_f32_16x16x32_bf16(pa0, oneb, lacc[0], 0, 0, 0);
      lacc[1] = __builtin_amdgcn_mfma_f32_16x16x32_bf16(pa1, oneb, lacc[1], 0, 0, 0);
#pragma unroll
      for (int nb2 = 0; nb2 < 4; ++nb2) {
        int drow = nb2 * 16 + l15;
        bf16x8 vf = *(const bf16x8*)((const char*)Vt[cur] + drow * 128 +
                                     (((kk * 4 + l4) ^ (drow & 7) ^ (drow >> 3)) << 4));
        accO[0][nb2] = __builtin_amdgcn_mfma_f32_16x16x32_bf16(pa0, vf, accO[0][nb2], 0, 0, 0);
        accO[1][nb2] = __builtin_amdgcn_mfma_f32_16x16x32_bf16(pa1, vf, accO[1][nb2], 0, 0, 0);
      }
    }
    __syncthreads();
  }

  const int bb = bh >> 4, hh = bh & 15;
#pragma unroll
  for (int g = 0; g < 2; ++g) {
#pragma unroll
    for (int rr = 0; rr < 4; ++rr) {
      float ls = __shfl(lacc[g][rr], l4 << 4);
      float rl = 1.f / ls;
      int qg = q0 + g * 64 + w * 16 + l4 * 4 + rr;
      size_t base = ((size_t)qg * B_ + bb) * D_ + hh * 64;
#pragma unroll
      for (int nb2 = 0; nb2 < 4; ++nb2)
        op[base + nb2 * 16 + l15] = f2bf(accO[g][nb2][rr] * rl);
    }
  }
}

// ---------------- layernorm over last dim (D=1024), bf16 input ----------------
__global__ __launch_bounds__(256) void layernorm_bf_k(
    const u16* __restrict__ y, const float* __restrict__ g, const float* __restrict__ be,
    float* __restrict__ of, u16* __restrict__ ob)
{
  int row = blockIdx.x, tid = threadIdx.x;
  uint2 raw = *(const uint2*)&y[(size_t)row * D_ + tid * 4];
  float v0 = bf2f(raw.x & 0xffffu), v1 = bf2f(raw.x >> 16);
  float v2 = bf2f(raw.y & 0xffffu), v3 = bf2f(raw.y >> 16);
  float s = (v0 + v1) + (v2 + v3);
  float ss = v0 * v0 + v1 * v1 + v2 * v2 + v3 * v3;
#pragma unroll
  for (int msk = 32; msk >= 1; msk >>= 1) {
    s += __shfl_xor(s, msk);
    ss += __shfl_xor(ss, msk);
  }
  __shared__ float rs[4], rss[4];
  if ((tid & 63) == 0) { rs[tid >> 6] = s; rss[tid >> 6] = ss; }
  __syncthreads();
  s = rs[0] + rs[1] + rs[2] + rs[3];
  ss = rss[0] + rss[1] + rss[2] + rss[3];
  float mu = s * (1.f / D_);
  float var = ss * (1.f / D_) - mu * mu;
  float rstd = rsqrtf(var + 1e-5f);
  int c = tid * 4;
  float o0 = (v0 - mu) * rstd * g[c + 0] + be[c + 0];
  float o1 = (v1 - mu) * rstd * g[c + 1] + be[c + 1];
  float o2 = (v2 - mu) * rstd * g[c + 2] + be[c + 2];
  float o3 = (v3 - mu) * rstd * g[c + 3] + be[c + 3];
  if (of) {
    float4 o = {o0, o1, o2, o3};
    *(float4*)&of[(size_t)row * D_ + c] = o;
  }
  if (ob) {
    uint2 r;
    r.x = (u32)f2bf(o0) | ((u32)f2bf(o1) << 16);
    r.y = (u32)f2bf(o2) | ((u32)f2bf(o3) << 16);
    *(uint2*)&ob[(size_t)row * D_ + c] = r;
  }
}

// ---------------- launch ----------------
extern "C" void kernel_launch(void* const* d_in, const int* in_sizes, int n_in,
                              void* d_out, int out_size, void* d_ws, size_t ws_size,
                              hipStream_t stream)
{
  const float* x   = (const float*)d_in[0];
  const float* Wq  = (const float*)d_in[1];
  const float* bq  = (const float*)d_in[2];
  const float* Wk  = (const float*)d_in[3];
  const float* bk  = (const float*)d_in[4];
  const float* Wv  = (const float*)d_in[5];
  const float* bv  = (const float*)d_in[6];
  const float* Wo  = (const float*)d_in[7];
  const float* bo  = (const float*)d_in[8];
  const float* W1f = (const float*)d_in[9];
  const float* b1  = (const float*)d_in[10];
  const float* W2f = (const float*)d_in[11];
  const float* b2  = (const float*)d_in[12];
  const float* g1  = (const float*)d_in[13];
  const float* be1 = (const float*)d_in[14];
  const float* g2  = (const float*)d_in[15];
  const float* be2 = (const float*)d_in[16];

  char* ws = (char*)d_ws;
  const size_t MB = 1024 * 1024;
  u16* WqT  = (u16*)(ws + 0 * MB);      // 8MB: WqT,WkT,WvT,WoT contiguous
  u16* WoT  = (u16*)(ws + 6 * MB);
  u16* W1T  = (u16*)(ws + 8 * MB);      // 8MB
  u16* W2T  = (u16*)(ws + 16 * MB);     // 8MB
  u16* xb   = (u16*)(ws + 24 * MB);     // 16MB
  u16* qp   = (u16*)(ws + 40 * MB);     // 48MB: qp,kp,vp
  u16* astd = (u16*)(ws + 88 * MB);     // 16MB
  u16* yb   = (u16*)(ws + 104 * MB);    // 16MB
  u16* x1b  = (u16*)(ws + 120 * MB);    // 16MB
  u16* hbuf = (u16*)(ws + 136 * MB);    // 64MB
  float* bcat = (float*)(ws + 200 * MB);// 12KB
  u16* kp = qp + 8388608;
  u16* vp = qp + 16777216;

  dim3 tb(32, 8);
  transpose_w4_k<<<dim3(32, 32, 4), tb, 0, stream>>>(Wq, Wk, Wv, Wo, WqT);
  transpose_w_k<<<dim3(128, 32), tb, 0, stream>>>(W1f, W1T, D_, DFF_);
  transpose_w_k<<<dim3(32, 128), tb, 0, stream>>>(W2f, W2T, DFF_, D_);
  f32_to_bf16_k<<<NT_ * D_ / 4 / 256, 256, 0, stream>>>(x, xb, NT_ * D_ / 4);
  bias_concat_k<<<12, 256, 0, stream>>>(bq, bk, bv, bcat);

  // fused QKV: [8192 x 3072], scattered to [b][h][l][d]; Q pre-scaled (256² tile)
  gemm8<3><<<dim3(12, 32), 512, 0, stream>>>(
      xb, WqT, bcat, nullptr, qp, NT_, 3072, D_);

  attn_fwd2<<<1024, 256, 0, stream>>>(qp, kp, vp, astd);

  gemm_pipe<5><<<dim3(8, 32), 512, 0, stream>>>(
      astd, WoT, bo, x, yb, NT_, D_, D_);
  layernorm_bf_k<<<NT_, 256, 0, stream>>>(yb, g1, be1, nullptr, x1b);
  gemm8<2><<<dim3(16, 32), 512, 0, stream>>>(
      x1b, W1T, b1, nullptr, hbuf, NT_, DFF_, D_);
  gemm_pipe<6><<<dim3(8, 32), 512, 0, stream>>>(
      hbuf, W2T, b2, x1b, yb, NT_, D_, DFF_);
  layernorm_bf_k<<<NT_, 256, 0, stream>>>(yb, g2, be2, (float*)d_out, nullptr);
}

// Round 14
// 421.613 us; speedup vs baseline: 1.0452x; 1.0424x over previous
//
#include <hip/hip_runtime.h>

#define L_   2048
#define B_   4
#define D_   1024
#define H_   16
#define DK_  64
#define DFF_ 4096
#define NT_  (L_*B_)   // 8192 tokens

typedef unsigned short u16;
typedef unsigned int   u32;
typedef __bf16 bf16x8 __attribute__((ext_vector_type(8)));
typedef float  f32x4  __attribute__((ext_vector_type(4)));

__device__ __forceinline__ u16 f2bf(float f) {
  u32 u = __float_as_uint(f);
  u += 0x7fffu + ((u >> 16) & 1u);
  return (u16)(u >> 16);
}
__device__ __forceinline__ float bf2f(u32 lo16) {
  return __uint_as_float(lo16 << 16);
}

#define GLDS16(g, l) __builtin_amdgcn_global_load_lds( \
    (const __attribute__((address_space(1))) void*)(g), \
    (__attribute__((address_space(3))) void*)(l), 16, 0, 0)

// log2(e)/sqrt(DK) folded into Q at projection time
#define SCQ_ 0.18033688011112042f

// ---------------- weight transpose f32 [K][N] -> bf16 [N][K] ----------------
__global__ __launch_bounds__(256) void transpose_w_k(
    const float* __restrict__ W, u16* __restrict__ Wt, int K, int N)
{
  __shared__ float tile[32][33];
  int n0 = blockIdx.x * 32, k0 = blockIdx.y * 32;
  int tx = threadIdx.x, ty = threadIdx.y;
#pragma unroll
  for (int i = ty; i < 32; i += 8)
    tile[i][tx] = W[(size_t)(k0 + i) * N + n0 + tx];
  __syncthreads();
#pragma unroll
  for (int i = ty; i < 32; i += 8)
    Wt[(size_t)(n0 + i) * K + k0 + tx] = f2bf(tile[tx][i]);
}

// batched 1024x1024 transpose for Wq,Wk,Wv,Wo -> contiguous dst
__global__ __launch_bounds__(256) void transpose_w4_k(
    const float* __restrict__ W0, const float* __restrict__ W1,
    const float* __restrict__ W2, const float* __restrict__ W3,
    u16* __restrict__ dst)
{
  __shared__ float tile[32][33];
  int z = blockIdx.z;
  const float* W = (z == 0) ? W0 : (z == 1) ? W1 : (z == 2) ? W2 : W3;
  u16* Wt = dst + (size_t)z * 1048576;
  int n0 = blockIdx.x * 32, k0 = blockIdx.y * 32;
  int tx = threadIdx.x, ty = threadIdx.y;
#pragma unroll
  for (int i = ty; i < 32; i += 8)
    tile[i][tx] = W[(size_t)(k0 + i) * 1024 + n0 + tx];
  __syncthreads();
#pragma unroll
  for (int i = ty; i < 32; i += 8)
    Wt[(size_t)(n0 + i) * 1024 + k0 + tx] = f2bf(tile[tx][i]);
}

// ---------------- f32 -> bf16 convert (vectorized) ----------------
__global__ __launch_bounds__(256) void f32_to_bf16_k(
    const float* __restrict__ in, u16* __restrict__ out, int n4)
{
  int i = blockIdx.x * 256 + threadIdx.x;
  if (i >= n4) return;
  float4 v = ((const float4*)in)[i];
  uint2 r;
  r.x = (u32)f2bf(v.x) | ((u32)f2bf(v.y) << 16);
  r.y = (u32)f2bf(v.z) | ((u32)f2bf(v.w) << 16);
  ((uint2*)out)[i] = r;
}

__global__ __launch_bounds__(256) void bias_concat_k(
    const float* __restrict__ bq, const float* __restrict__ bk,
    const float* __restrict__ bv, float* __restrict__ o)
{
  int i = blockIdx.x * 256 + threadIdx.x;
  float v = (i < 1024) ? bq[i] : ((i < 2048) ? bk[i - 1024] : bv[i - 2048]);
  o[i] = v;
}

// ---------------- 256x256 4-phase GEMM (m201-style geometry) ---------------
template<int EPI>
__global__ __launch_bounds__(512, 2)
void gemm8(const u16* __restrict__ A, const u16* __restrict__ Bt,
           const float* __restrict__ bias, const void* __restrict__ res,
           u16* __restrict__ outb, int M, int N, int K)
{
  constexpr int BM = 256, BN = 256, BK = 64;
  constexpr int ABYTES = BM * BK * 2;        // 32768
  constexpr int BUFB = (BM + BN) * BK * 2;   // 65536
  constexpr int NGL = BUFB / 8192;           // 8 glds per K-tile
  __shared__ char SM[2 * BUFB];              // 128KB

  const int tid = threadIdx.x;
  const int w = tid >> 6, lane = tid & 63;
  const int l15 = lane & 15, l4 = lane >> 4;
  const int NK = K >> 6;

  const int gx = gridDim.x;
  int nwg = gx * gridDim.y;
  int id = blockIdx.y * gx + blockIdx.x;
  int q = nwg >> 3, r = nwg & 7;
  int xcd = id & 7, idx = id >> 3;
  int wg = (xcd < r ? xcd * (q + 1) : r * (q + 1) + (xcd - r) * q) + idx;
  const int m0 = (wg / gx) * BM, n0 = (wg % gx) * BN;
  const int wm = (w >> 2) * 128, wn = (w & 3) * 64;

  const u16* gsrc[NGL];
#pragma unroll
  for (int u = 0; u < NGL; ++u) {
    int o = u * 8192 + tid * 16;
    int row; const u16* base;
    if (o < ABYTES) { row = o >> 7; base = A + (size_t)(m0 + row) * K; }
    else { row = (o - ABYTES) >> 7; base = Bt + (size_t)(n0 + row) * K; }
    int col8 = ((o >> 4) & 7) ^ (row & 7);
    gsrc[u] = base + col8 * 8;
  }

  auto stage = [&](int tt, int u, char* dst) {
    GLDS16(gsrc[u] + (size_t)tt * BK, dst + u * 8192 + w * 1024);
  };

#pragma unroll
  for (int u = 0; u < NGL; ++u) stage(0, u, SM);
  asm volatile("s_waitcnt vmcnt(0)" ::: "memory");
  __builtin_amdgcn_s_barrier();

  f32x4 acc[8][4];
#pragma unroll
  for (int i = 0; i < 8; ++i)
#pragma unroll
    for (int j = 0; j < 4; ++j) acc[i][j] = (f32x4){0.f, 0.f, 0.f, 0.f};

  for (int t = 0; t < NK; ++t) {
    const char* rb = SM + (t & 1) * BUFB;
    char* wb = SM + ((t + 1) & 1) * BUFB;
    const int tt = (t + 1 < NK) ? t + 1 : 0;   // dummy tail
    bf16x8 bfr[4];
#pragma unroll
    for (int ph = 0; ph < 4; ++ph) {
      const int kk = ph >> 1, mh = ph & 1;
      bf16x8 af[4];
#pragma unroll
      for (int mi = 0; mi < 4; ++mi) {
        int row = wm + mh * 64 + mi * 16 + l15;
        af[mi] = *(const bf16x8*)(rb + row * 128 +
                                  (((kk * 4 + l4) ^ (row & 7)) << 4));
      }
      if (mh == 0) {
#pragma unroll
        for (int nj = 0; nj < 4; ++nj) {
          int row = wn + nj * 16 + l15;
          bfr[nj] = *(const bf16x8*)(rb + ABYTES + row * 128 +
                                     (((kk * 4 + l4) ^ (row & 7)) << 4));
        }
      }
      if (ph == 0)      { stage(tt, 0, wb); stage(tt, 1, wb); stage(tt, 2, wb); }
      else if (ph == 1) { stage(tt, 3, wb); stage(tt, 4, wb); stage(tt, 5, wb); }
      else if (ph == 2) { stage(tt, 6, wb); stage(tt, 7, wb); }
      __builtin_amdgcn_s_barrier();
      asm volatile("s_waitcnt lgkmcnt(0)" ::: "memory");
      __builtin_amdgcn_sched_barrier(0);
      __builtin_amdgcn_s_setprio(1);
#pragma unroll
      for (int mi = 0; mi < 4; ++mi)
#pragma unroll
        for (int nj = 0; nj < 4; ++nj)
          acc[mh * 4 + mi][nj] = __builtin_amdgcn_mfma_f32_16x16x32_bf16(
              af[mi], bfr[nj], acc[mh * 4 + mi][nj], 0, 0, 0);
      __builtin_amdgcn_s_setprio(0);
      if (ph == 3)
        asm volatile("s_waitcnt vmcnt(0)" ::: "memory");  // t+1 landed
      __builtin_amdgcn_s_barrier();
    }
  }
  asm volatile("s_waitcnt vmcnt(0)" ::: "memory");

  const int gm = m0 + wm + l4 * 4;
  const int gn = n0 + wn + l15;
#pragma unroll
  for (int mi = 0; mi < 8; ++mi) {
#pragma unroll
    for (int nj = 0; nj < 4; ++nj) {
      int col = gn + nj * 16;
      float bv = bias[col];
#pragma unroll
      for (int rr = 0; rr < 4; ++rr) {
        int row = gm + mi * 16 + rr;
        float v = acc[mi][nj][rr] + bv;
        if (EPI == 2) {
          float gv = 0.5f * v * (1.f + erff(v * 0.70710678118654752f));
          outb[(size_t)row * N + col] = f2bf(gv);
        } else if (EPI == 3) {
          int which = col >> 10, c1 = col & 1023;
          int ll = row >> 2, bb = row & 3;
          int hh = c1 >> 6, dd = c1 & 63;
          if (which == 0) v *= SCQ_;
          outb[(size_t)which * 8388608 +
               ((((size_t)(bb * H_ + hh)) * L_ + ll) << 6) + dd] = f2bf(v);
        } else if (EPI == 5) {
          size_t idxo = (size_t)row * N + col;
          outb[idxo] = f2bf(v + ((const float*)res)[idxo]);
        } else {
          size_t idxo = (size_t)row * N + col;
          outb[idxo] = f2bf(v + bf2f(((const u16*)res)[idxo]));
        }
      }
    }
  }
}

// ---------------- r10 256x128 GEMM (kept for Wo/W2, N=1024 grids) ----------
template<int EPI>
__global__ __launch_bounds__(512, 2)
void gemm_pipe(const u16* __restrict__ A, const u16* __restrict__ Bt,
               const float* __restrict__ bias, const void* __restrict__ res,
               u16* __restrict__ outb, int M, int N, int K)
{
  constexpr int BM = 256, BN = 128, BK = 64;
  constexpr int ABYTES = BM * BK * 2;        // 32768
  constexpr int BUFB = (BM + BN) * BK * 2;   // 49152
  __shared__ char SM[3 * BUFB];              // 144KB ring

  const int tid = threadIdx.x;
  const int w = tid >> 6, lane = tid & 63;
  const int l15 = lane & 15, l4 = lane >> 4;
  const int NK = K >> 6;

  const int gx = gridDim.x;
  int nwg = gx * gridDim.y;
  int id = blockIdx.y * gx + blockIdx.x;
  int q = nwg >> 3, r = nwg & 7;
  int xcd = id & 7, idx = id >> 3;
  int wg = (xcd < r ? xcd * (q + 1) : r * (q + 1) + (xcd - r) * q) + idx;
  const int m0 = (wg / gx) * BM, n0 = (wg % gx) * BN;
  const int wm = (w >> 1) * 64, wn = (w & 1) * 64;

  const u16* gsrc[6];
#pragma unroll
  for (int u = 0; u < 6; ++u) {
    int o = u * 8192 + tid * 16;
    int row; const u16* base;
    if (o < ABYTES) {
      row = o >> 7;
      base = A + (size_t)(m0 + row) * K;
    } else {
      int ob = o - ABYTES;
      row = ob >> 7;
      base = Bt + (size_t)(n0 + row) * K;
    }
    int col8 = ((o >> 4) & 7) ^ (row & 7);
    gsrc[u] = base + col8 * 8;
  }

  auto stage = [&](int t, int u) {
    const u16* s = gsrc[u] + (size_t)((t < NK) ? t : 0) * BK;
    GLDS16(s, SM + (t % 3) * BUFB + u * 8192 + w * 1024);
  };

  for (int tt = 0; tt < 2; ++tt)
#pragma unroll
    for (int u = 0; u < 6; ++u) stage(tt, u);
  asm volatile("s_waitcnt vmcnt(6)" ::: "memory");
  asm volatile("s_barrier" ::: "memory");

  f32x4 acc[4][4];
#pragma unroll
  for (int i = 0; i < 4; ++i)
#pragma unroll
    for (int j = 0; j < 4; ++j) acc[i][j] = (f32x4){0.f, 0.f, 0.f, 0.f};

  for (int t = 0; t < NK; ++t) {
    const char* rb = SM + (t % 3) * BUFB;
    const int tn = t + 2;
#pragma unroll
    for (int ph = 0; ph < 2; ++ph) {
      bf16x8 af[4], bfr[4];
#pragma unroll
      for (int mi = 0; mi < 4; ++mi) {
        int row = wm + mi * 16 + l15;
        af[mi] = *(const bf16x8*)(rb + row * 128 +
                                  (((ph * 4 + l4) ^ (l15 & 7)) << 4));
      }
      stage(tn, ph * 3 + 0);
#pragma unroll
      for (int nj = 0; nj < 4; ++nj) {
        int row = wn + nj * 16 + l15;
        bfr[nj] = *(const bf16x8*)(rb + ABYTES + row * 128 +
                                   (((ph * 4 + l4) ^ (l15 & 7)) << 4));
      }
      stage(tn, ph * 3 + 1);
      stage(tn, ph * 3 + 2);
      __builtin_amdgcn_s_setprio(1);
#pragma unroll
      for (int mi = 0; mi < 4; ++mi)
#pragma unroll
        for (int nj = 0; nj < 4; ++nj)
          acc[mi][nj] = __builtin_amdgcn_mfma_f32_16x16x32_bf16(
              af[mi], bfr[nj], acc[mi][nj], 0, 0, 0);
      __builtin_amdgcn_s_setprio(0);
    }
    asm volatile("s_waitcnt lgkmcnt(0)" ::: "memory");
    asm volatile("s_waitcnt vmcnt(6)" ::: "memory");
    asm volatile("s_barrier" ::: "memory");
  }
  asm volatile("s_waitcnt vmcnt(0)" ::: "memory");

  const int gm = m0 + wm + l4 * 4;
  const int gn = n0 + wn + l15;
#pragma unroll
  for (int mi = 0; mi < 4; ++mi) {
#pragma unroll
    for (int nj = 0; nj < 4; ++nj) {
      int col = gn + nj * 16;
      float bv = bias[col];
#pragma unroll
      for (int rr = 0; rr < 4; ++rr) {
        int row = gm + mi * 16 + rr;
        float v = acc[mi][nj][rr] + bv;
        if (EPI == 5) {
          size_t idxo = (size_t)row * N + col;
          outb[idxo] = f2bf(v + ((const float*)res)[idxo]);
        } else {
          size_t idxo = (size_t)row * N + col;
          outb[idxo] = f2bf(v + bf2f(((const u16*)res)[idxo]));
        }
      }
    }
  }
}

// ---------------- flash attention fwd v8: 8 waves, 256 q/block -------------
// No-max softmax (exact after O/l; bounded scores), MFMA row-sums, K staged
// row-permuted+swizzled via 1 global_load_lds per wave, V transposed in-LDS
// (2x uint2 + 4 perm + 4 ds_write per thread), double-buffered prefetch.
__global__ __launch_bounds__(512, 2)
void attn_fwd2(const u16* __restrict__ qp, const u16* __restrict__ kp,
               const u16* __restrict__ vp, u16* __restrict__ op)
{
  __shared__ u16 Ks[2][64 * 64];
  __shared__ u16 Vt[2][64 * 64];
  const int tid = threadIdx.x, w = tid >> 6, lane = tid & 63;
  const int l15 = lane & 15, l4 = lane >> 4;
  const int n = blockIdx.x;            // 512 blocks = 8 XCD x 8 qi x 8 bh-high
  const int bh = (n & 7) | ((n >> 6) << 3);
  const int qi = (n >> 3) & 7;
  const int q0 = qi * 256;
  const u16* qb = qp + (size_t)bh * L_ * DK_;
  const u16* kb = kp + (size_t)bh * L_ * DK_;
  const u16* vb = vp + (size_t)bh * L_ * DK_;

  bf16x8 qf[2][2];
#pragma unroll
  for (int g = 0; g < 2; ++g)
#pragma unroll
    for (int kk = 0; kk < 2; ++kk)
      qf[g][kk] = *(const bf16x8*)&qb[(size_t)(q0 + g * 128 + w * 16 + l15) * DK_ +
                                      kk * 32 + l4 * 8];

  f32x4 accO[2][4];
  f32x4 lacc[2];
#pragma unroll
  for (int g = 0; g < 2; ++g) {
#pragma unroll
    for (int i = 0; i < 4; ++i) accO[g][i] = (f32x4){0.f, 0.f, 0.f, 0.f};
    lacc[g] = (f32x4){0.f, 0.f, 0.f, 0.f};
  }

  bf16x8 oneb;
  {
    u32 ob = (l15 == 0) ? 0x3f803f80u : 0u;
#pragma unroll
    for (int j = 0; j < 4; ++j) ((u32*)&oneb)[j] = ob;
  }

  // K staging: rho = tid>>3 in [0,64), each wave stages 8 rows (1KB, 1 GLDS)
  int rho0 = tid >> 3, cseg = tid & 7;
  int kv0 = (rho0 & 32) | ((rho0 & 12) << 1) | ((rho0 & 16) >> 2) | (rho0 & 3);
  const u16* ksrc0 = kb + (size_t)kv0 * DK_ + ((cseg ^ (rho0 & 7)) << 3);

  // V staging: thread handles kv-pair vkvp = tid>>4, d-group vdg = tid&15
  // (4 d values); 2 uint2 loads + 4 perms + 4 u32 swizzled writes.
  const int vdg = tid & 15, vkvp = tid >> 4;
  const u16* vsrc = vb + (size_t)(vkvp * 2) * DK_ + vdg * 4;
  u32 voff[4];
#pragma unroll
  for (int dd = 0; dd < 4; ++dd) {
    int d = vdg * 4 + dd;
    voff[dd] = d * 128 +
        ((((vkvp >> 2) ^ (d & 7) ^ (d >> 3)) << 4) | ((vkvp & 3) << 2));
  }

  auto packV = [&](int buf, uint2 a, uint2 b) {
    *(u32*)((char*)Vt[buf] + voff[0]) = __builtin_amdgcn_perm(b.x, a.x, 0x05040100u);
    *(u32*)((char*)Vt[buf] + voff[1]) = __builtin_amdgcn_perm(b.x, a.x, 0x07060302u);
    *(u32*)((char*)Vt[buf] + voff[2]) = __builtin_amdgcn_perm(b.y, a.y, 0x05040100u);
    *(u32*)((char*)Vt[buf] + voff[3]) = __builtin_amdgcn_perm(b.y, a.y, 0x07060302u);
  };

  auto exp_pack = [&](f32x4 (&s)[4], u32 (&pk)[2][4]) {
#pragma unroll
    for (int i = 0; i < 4; ++i)
#pragma unroll
      for (int rr = 0; rr < 4; ++rr) s[i][rr] = __builtin_amdgcn_exp2f(s[i][rr]);
#pragma unroll
    for (int kk = 0; kk < 2; ++kk)
#pragma unroll
      for (int j2 = 0; j2 < 4; ++j2) {
        int nb = kk * 2 + (j2 >> 1);
        int rr = (j2 & 1) * 2;
        u32 rres;
        asm("v_cvt_pk_bf16_f32 %0, %1, %2" : "=v"(rres)
            : "v"(s[nb][rr]), "v"(s[nb][rr + 1]));
        pk[kk][j2] = rres;
      }
  };

  // prologue: stage tile 0 into buf 0
  {
    uint2 a = *(const uint2*)vsrc;
    uint2 b = *(const uint2*)(vsrc + DK_);
    GLDS16(ksrc0, &Ks[0][w * 512]);
    packV(0, a, b);
  }
  __syncthreads();

  constexpr int NTI = L_ / 64;   // 32
  for (int t = 0; t < NTI; ++t) {
    const int cur = t & 1;
    const bool pf = (t + 1 < NTI);
    const int tn = pf ? t + 1 : t;

    // issue next-tile loads FIRST (V to regs, K via global_load_lds)
    uint2 va = *(const uint2*)(vsrc + (size_t)(tn * 64) * DK_);
    uint2 vbv = *(const uint2*)(vsrc + (size_t)(tn * 64) * DK_ + DK_);
    if (pf)
      GLDS16(ksrc0 + (size_t)((t + 1) * 64) * DK_, &Ks[cur ^ 1][w * 512]);

    // S^T = K_perm * Q^T for both q-groups (kf shared)
    f32x4 s0[4], s1[4];
#pragma unroll
    for (int i = 0; i < 4; ++i) {
      s0[i] = (f32x4){0.f, 0.f, 0.f, 0.f};
      s1[i] = (f32x4){0.f, 0.f, 0.f, 0.f};
    }
#pragma unroll
    for (int kk = 0; kk < 2; ++kk) {
#pragma unroll
      for (int nb = 0; nb < 4; ++nb) {
        int row = nb * 16 + l15;
        bf16x8 kf = *(const bf16x8*)((const char*)Ks[cur] + row * 128 +
                                     (((kk * 4 + l4) ^ (row & 7)) << 4));
        s0[nb] = __builtin_amdgcn_mfma_f32_16x16x32_bf16(kf, qf[0][kk], s0[nb], 0, 0, 0);
        s1[nb] = __builtin_amdgcn_mfma_f32_16x16x32_bf16(kf, qf[1][kk], s1[nb], 0, 0, 0);
      }
    }

    u32 pk0[2][4], pk1[2][4];
    exp_pack(s0, pk0);
    exp_pack(s1, pk1);

    // write V(t+1) into buf^1 (loads have had the QK^T+exp phase to land)
    if (pf) packV(cur ^ 1, va, vbv);

    // O += P @ V ; row-sums l += P @ ones (both groups, vf shared)
#pragma unroll
    for (int kk = 0; kk < 2; ++kk) {
      bf16x8 pa0, pa1;
      ((u32*)&pa0)[0] = pk0[kk][0]; ((u32*)&pa0)[1] = pk0[kk][1];
      ((u32*)&pa0)[2] = pk0[kk][2]; ((u32*)&pa0)[3] = pk0[kk][3];
      ((u32*)&pa1)[0] = pk1[kk][0]; ((u32*)&pa1)[1] = pk1[kk][1];
      ((u32*)&pa1)[2] = pk1[kk][2]; ((u32*)&pa1)[3] = pk1[kk][3];
      lacc[0] = __builtin_amdgcn_mfma_f32_16x16x32_bf16(pa0, oneb, lacc[0], 0, 0, 0);
      lacc[1] = __builtin_amdgcn_mfma_f32_16x16x32_bf16(pa1, oneb, lacc[1], 0, 0, 0);
#pragma unroll
      for (int nb2 = 0; nb2 < 4; ++nb2) {
        int drow = nb2 * 16 + l15;
        bf16x8 vf = *(const bf16x8*)((const char*)Vt[cur] + drow * 128 +
                                     (((kk * 4 + l4) ^ (drow & 7) ^ (drow >> 3)) << 4));
        accO[0][nb2] = __builtin_amdgcn_mfma_f32_16x16x32_bf16(pa0, vf, accO[0][nb2], 0, 0, 0);
        accO[1][nb2] = __builtin_amdgcn_mfma_f32_16x16x32_bf16(pa1, vf, accO[1][nb2], 0, 0, 0);
      }
    }
    __syncthreads();   // drains K glds -> buf^1 valid for t+1
  }

  // epilogue: lsum for q=l4*4+rr lives at lane (l4<<4), element rr
  const int bb = bh >> 4, hh = bh & 15;
#pragma unroll
  for (int g = 0; g < 2; ++g) {
#pragma unroll
    for (int rr = 0; rr < 4; ++rr) {
      float ls = __shfl(lacc[g][rr], l4 << 4);
      float rl = 1.f / ls;
      int qg = q0 + g * 128 + w * 16 + l4 * 4 + rr;
      size_t base = ((size_t)qg * B_ + bb) * D_ + hh * 64;
#pragma unroll
      for (int nb2 = 0; nb2 < 4; ++nb2)
        op[base + nb2 * 16 + l15] = f2bf(accO[g][nb2][rr] * rl);
    }
  }
}

// ---------------- layernorm over last dim (D=1024), bf16 input ----------------
__global__ __launch_bounds__(256) void layernorm_bf_k(
    const u16* __restrict__ y, const float* __restrict__ g, const float* __restrict__ be,
    float* __restrict__ of, u16* __restrict__ ob)
{
  int row = blockIdx.x, tid = threadIdx.x;
  uint2 raw = *(const uint2*)&y[(size_t)row * D_ + tid * 4];
  float v0 = bf2f(raw.x & 0xffffu), v1 = bf2f(raw.x >> 16);
  float v2 = bf2f(raw.y & 0xffffu), v3 = bf2f(raw.y >> 16);
  float s = (v0 + v1) + (v2 + v3);
  float ss = v0 * v0 + v1 * v1 + v2 * v2 + v3 * v3;
#pragma unroll
  for (int msk = 32; msk >= 1; msk >>= 1) {
    s += __shfl_xor(s, msk);
    ss += __shfl_xor(ss, msk);
  }
  __shared__ float rs[4], rss[4];
  if ((tid & 63) == 0) { rs[tid >> 6] = s; rss[tid >> 6] = ss; }
  __syncthreads();
  s = rs[0] + rs[1] + rs[2] + rs[3];
  ss = rss[0] + rss[1] + rss[2] + rss[3];
  float mu = s * (1.f / D_);
  float var = ss * (1.f / D_) - mu * mu;
  float rstd = rsqrtf(var + 1e-5f);
  int c = tid * 4;
  float o0 = (v0 - mu) * rstd * g[c + 0] + be[c + 0];
  float o1 = (v1 - mu) * rstd * g[c + 1] + be[c + 1];
  float o2 = (v2 - mu) * rstd * g[c + 2] + be[c + 2];
  float o3 = (v3 - mu) * rstd * g[c + 3] + be[c + 3];
  if (of) {
    float4 o = {o0, o1, o2, o3};
    *(float4*)&of[(size_t)row * D_ + c] = o;
  }
  if (ob) {
    uint2 r;
    r.x = (u32)f2bf(o0) | ((u32)f2bf(o1) << 16);
    r.y = (u32)f2bf(o2) | ((u32)f2bf(o3) << 16);
    *(uint2*)&ob[(size_t)row * D_ + c] = r;
  }
}

// ---------------- launch ----------------
extern "C" void kernel_launch(void* const* d_in, const int* in_sizes, int n_in,
                              void* d_out, int out_size, void* d_ws, size_t ws_size,
                              hipStream_t stream)
{
  const float* x   = (const float*)d_in[0];
  const float* Wq  = (const float*)d_in[1];
  const float* bq  = (const float*)d_in[2];
  const float* Wk  = (const float*)d_in[3];
  const float* bk  = (const float*)d_in[4];
  const float* Wv  = (const float*)d_in[5];
  const float* bv  = (const float*)d_in[6];
  const float* Wo  = (const float*)d_in[7];
  const float* bo  = (const float*)d_in[8];
  const float* W1f = (const float*)d_in[9];
  const float* b1  = (const float*)d_in[10];
  const float* W2f = (const float*)d_in[11];
  const float* b2  = (const float*)d_in[12];
  const float* g1  = (const float*)d_in[13];
  const float* be1 = (const float*)d_in[14];
  const float* g2  = (const float*)d_in[15];
  const float* be2 = (const float*)d_in[16];

  char* ws = (char*)d_ws;
  const size_t MB = 1024 * 1024;
  u16* WqT  = (u16*)(ws + 0 * MB);      // 8MB: WqT,WkT,WvT,WoT contiguous
  u16* WoT  = (u16*)(ws + 6 * MB);
  u16* W1T  = (u16*)(ws + 8 * MB);      // 8MB
  u16* W2T  = (u16*)(ws + 16 * MB);     // 8MB
  u16* xb   = (u16*)(ws + 24 * MB);     // 16MB
  u16* qp   = (u16*)(ws + 40 * MB);     // 48MB: qp,kp,vp
  u16* astd = (u16*)(ws + 88 * MB);     // 16MB
  u16* yb   = (u16*)(ws + 104 * MB);    // 16MB
  u16* x1b  = (u16*)(ws + 120 * MB);    // 16MB
  u16* hbuf = (u16*)(ws + 136 * MB);    // 64MB
  float* bcat = (float*)(ws + 200 * MB);// 12KB
  u16* kp = qp + 8388608;
  u16* vp = qp + 16777216;

  dim3 tb(32, 8);
  transpose_w4_k<<<dim3(32, 32, 4), tb, 0, stream>>>(Wq, Wk, Wv, Wo, WqT);
  transpose_w_k<<<dim3(128, 32), tb, 0, stream>>>(W1f, W1T, D_, DFF_);
  transpose_w_k<<<dim3(32, 128), tb, 0, stream>>>(W2f, W2T, DFF_, D_);
  f32_to_bf16_k<<<NT_ * D_ / 4 / 256, 256, 0, stream>>>(x, xb, NT_ * D_ / 4);
  bias_concat_k<<<12, 256, 0, stream>>>(bq, bk, bv, bcat);

  // fused QKV: [8192 x 3072], scattered to [b][h][l][d]; Q pre-scaled (256²)
  gemm8<3><<<dim3(12, 32), 512, 0, stream>>>(
      xb, WqT, bcat, nullptr, qp, NT_, 3072, D_);

  attn_fwd2<<<512, 512, 0, stream>>>(qp, kp, vp, astd);

  gemm_pipe<5><<<dim3(8, 32), 512, 0, stream>>>(
      astd, WoT, bo, x, yb, NT_, D_, D_);
  layernorm_bf_k<<<NT_, 256, 0, stream>>>(yb, g1, be1, nullptr, x1b);
  gemm8<2><<<dim3(16, 32), 512, 0, stream>>>(
      x1b, W1T, b1, nullptr, hbuf, NT_, DFF_, D_);
  gemm_pipe<6><<<dim3(8, 32), 512, 0, stream>>>(
      hbuf, W2T, b2, x1b, yb, NT_, D_, DFF_);
  layernorm_bf_k<<<NT_, 256, 0, stream>>>(yb, g2, be2, (float*)d_out, nullptr);
}